// Round 1
// baseline (1837.862 us; speedup 1.0000x reference)
//
#include <hip/hip_runtime.h>

// VectorQuantizer (eval fwd): inputs [64,64,32,32] f32 NCHW, embedding [1024,64] f32.
// Outputs concatenated: quantized [64,64,32,32] f32, loss scalar, perplexity scalar.
//
// N = 64*32*32 = 65536 pixel rows, D = 64, K = 1024.
// ws layout (floats): [0..1023] e2 (||e_k||^2), [1024..2047] counts (uint32), [2048] loss accum.

#define K_CODES 1024
#define DIM 64
#define HW 1024          // 32*32
#define N_ROWS 65536
#define OUT_ELEMS 4194304  // 64*64*32*32

__global__ void vq_init(const float* __restrict__ emb, float* __restrict__ ws) {
    const int k = blockIdx.x * blockDim.x + threadIdx.x;  // 1024 threads total
    if (k < K_CODES) {
        const float4* e4 = reinterpret_cast<const float4*>(emb + k * DIM);
        float s = 0.f;
#pragma unroll
        for (int i = 0; i < DIM / 4; ++i) {
            float4 v = e4[i];
            s += v.x * v.x + v.y * v.y + v.z * v.z + v.w * v.w;
        }
        ws[k] = s;
        reinterpret_cast<unsigned int*>(ws)[K_CODES + k] = 0u;
    }
    if (blockIdx.x == 0 && threadIdx.x == 0) ws[2048] = 0.f;
}

__global__ __launch_bounds__(256, 4) void vq_main(
    const float* __restrict__ in, const float* __restrict__ emb,
    float* __restrict__ out, float* __restrict__ ws)
{
    const int t    = blockIdx.x * blockDim.x + threadIdx.x;
    const int row  = t >> 2;     // 0..65535
    const int part = t & 3;      // handles codes k ≡ part (mod 4)
    const int b    = row >> 10;
    const int hw   = row & 1023;

    const float* xin = in + b * (DIM * HW) + hw;

    float x[DIM];
#pragma unroll
    for (int c = 0; c < DIM; ++c) x[c] = xin[c * HW];

    const float* e2 = ws;

    float best  = 3.4e38f;
    int   bestk = 0;

    // codes k = 4*j + part
    const float* ep = emb + part * DIM;
    for (int j = 0; j < K_CODES / 4; ++j) {
        const float4* e4 = reinterpret_cast<const float4*>(ep + j * (4 * DIM));
        float e2v = e2[4 * j + part];
        float acc[4] = {0.f, 0.f, 0.f, 0.f};
#pragma unroll
        for (int i = 0; i < 16; ++i) {
            float4 v = e4[i];
            acc[i & 3] = fmaf(v.x, x[4 * i + 0], acc[i & 3]);
            acc[i & 3] = fmaf(v.y, x[4 * i + 1], acc[i & 3]);
            acc[i & 3] = fmaf(v.z, x[4 * i + 2], acc[i & 3]);
            acc[i & 3] = fmaf(v.w, x[4 * i + 3], acc[i & 3]);
        }
        float dot  = (acc[0] + acc[1]) + (acc[2] + acc[3]);
        float dist = fmaf(-2.f, dot, e2v);   // ||e||^2 - 2 x.e  (row-constant ||x||^2 dropped)
        int   k    = 4 * j + part;
        if (dist < best) { best = dist; bestk = k; }
    }

    // merge argmin across the 4 partner lanes; lex (dist, k) min == first-occurrence argmin
#pragma unroll
    for (int off = 1; off < 4; off <<= 1) {
        float od = __shfl_xor(best, off, 64);
        int   ok = __shfl_xor(bestk, off, 64);
        if (od < best || (od == best && ok < bestk)) { best = od; bestk = ok; }
    }

    // counts histogram: one increment per row
    if (part == 0) {
        atomicAdd(reinterpret_cast<unsigned int*>(ws) + K_CODES + bestk, 1u);
    }

    // epilogue: lane `part` owns channels [16*part, 16*part+16)
    const float4* eq = reinterpret_cast<const float4*>(emb + bestk * DIM + 16 * part);
    float* outp = out + b * (DIM * HW) + hw;
    float lsum = 0.f;
#pragma unroll
    for (int i = 0; i < 4; ++i) {
        float4 q = eq[i];
        const int c0 = 16 * part + 4 * i;
        float d0 = q.x - x[c0 + 0];
        float d1 = q.y - x[c0 + 1];
        float d2 = q.z - x[c0 + 2];
        float d3 = q.w - x[c0 + 3];
        lsum += d0 * d0 + d1 * d1 + d2 * d2 + d3 * d3;
        // STE arithmetic replicated: out = x + (q - x)
        outp[(c0 + 0) * HW] = x[c0 + 0] + d0;
        outp[(c0 + 1) * HW] = x[c0 + 1] + d1;
        outp[(c0 + 2) * HW] = x[c0 + 2] + d2;
        outp[(c0 + 3) * HW] = x[c0 + 3] + d3;
    }

    // block-reduce loss partial -> one atomic per block
#pragma unroll
    for (int off = 32; off; off >>= 1) lsum += __shfl_down(lsum, off, 64);
    __shared__ float lred[4];
    const int lane = threadIdx.x & 63;
    const int wid  = threadIdx.x >> 6;
    if (lane == 0) lred[wid] = lsum;
    __syncthreads();
    if (threadIdx.x == 0) {
        atomicAdd(ws + 2048, (lred[0] + lred[1]) + (lred[2] + lred[3]));
    }
}

__global__ void vq_final(float* __restrict__ out, const float* __restrict__ ws) {
    __shared__ float red[16];
    const int t = threadIdx.x;  // 1024 threads
    const unsigned int* counts = reinterpret_cast<const unsigned int*>(ws) + K_CODES;
    float p = (float)counts[t] * (1.0f / 65536.f);
    float v = p * logf(p + 1e-10f);
#pragma unroll
    for (int off = 32; off; off >>= 1) v += __shfl_down(v, off, 64);
    if ((t & 63) == 0) red[t >> 6] = v;
    __syncthreads();
    if (t == 0) {
        float s = 0.f;
#pragma unroll
        for (int i = 0; i < 16; ++i) s += red[i];
        out[OUT_ELEMS]     = 0.25f * (1.0f / (float)OUT_ELEMS) * ws[2048];  // loss
        out[OUT_ELEMS + 1] = expf(-s);                                       // perplexity
    }
}

extern "C" void kernel_launch(void* const* d_in, const int* in_sizes, int n_in,
                              void* d_out, int out_size, void* d_ws, size_t ws_size,
                              hipStream_t stream) {
    const float* in  = (const float*)d_in[0];
    const float* emb = (const float*)d_in[1];
    float* out = (float*)d_out;
    float* ws  = (float*)d_ws;

    vq_init<<<4, 256, 0, stream>>>(emb, ws);
    vq_main<<<N_ROWS * 4 / 256, 256, 0, stream>>>(in, emb, out, ws);
    vq_final<<<1, 1024, 0, stream>>>(out, ws);
}

// Round 2
// 199.784 us; speedup vs baseline: 9.1992x; 9.1992x over previous
//
#include <hip/hip_runtime.h>

// VectorQuantizer (eval fwd): inputs [64,64,32,32] f32 NCHW, embedding [1024,64] f32.
// Outputs concatenated: quantized [64,64,32,32] f32, loss scalar, perplexity scalar.
//
// Strategy: distances = ||e_k||^2 - 2 x.e_k (row-constant ||x||^2 dropped).
// All lanes scan the SAME code k simultaneously -> embedding loads are
// wave-uniform -> compiler emits s_load (scalar pipe) -> inner loop is pure
// v_fma with SGPR operands. Parallelism from splitting the 1024 codes into
// SPLIT block-uniform ranges (partial argmin merged in a second kernel).

#define K_CODES 1024
#define DIM 64
#define HW 1024          // 32*32
#define N_ROWS 65536
#define OUT_ELEMS 4194304
#define SPLIT 4
#define KPER (K_CODES / SPLIT)

// ws layout (float indices)
#define WS_E2   0                       // 1024 floats: ||e_k||^2
#define WS_CNT  1024                    // 1024 u32: counts
#define WS_LOSS 2048                    // 1 float
#define WS_PD   4096                    // SPLIT*N_ROWS floats: partial dists
#define WS_PK   (4096 + SPLIT * N_ROWS) // SPLIT*N_ROWS ints: partial ks
#define WS_BYTES_NEEDED ((size_t)(WS_PK + SPLIT * N_ROWS) * 4)

__global__ void vq_init(const float* __restrict__ emb, float* __restrict__ ws) {
    const int k = blockIdx.x * blockDim.x + threadIdx.x;  // 1024 threads total
    if (k < K_CODES) {
        const float4* e4 = reinterpret_cast<const float4*>(emb + k * DIM);
        float s = 0.f;
#pragma unroll
        for (int i = 0; i < DIM / 4; ++i) {
            float4 v = e4[i];
            s += v.x * v.x + v.y * v.y + v.z * v.z + v.w * v.w;
        }
        ws[WS_E2 + k] = s;
        reinterpret_cast<unsigned int*>(ws)[WS_CNT + k] = 0u;
    }
    if (blockIdx.x == 0 && threadIdx.x == 0) ws[WS_LOSS] = 0.f;
}

// ---- argmin over one code range; all embedding accesses wave-uniform ----
__global__ __launch_bounds__(256, 4) void vq_argmin(
    const float* __restrict__ in, const float* __restrict__ emb,
    float* __restrict__ ws)
{
    const int blk    = blockIdx.x;
    const int split  = blk & (SPLIT - 1);
    const int rowblk = blk >> 2;              // log2(SPLIT)
    const int row    = rowblk * 256 + threadIdx.x;
    const int b      = row >> 10;
    const int hw     = row & 1023;

    const float* xin = in + b * (DIM * HW) + hw;
    float x[DIM];
#pragma unroll
    for (int c = 0; c < DIM; ++c) x[c] = xin[c * HW];

    const float* e2 = ws + WS_E2;
    float best  = 3.4e38f;
    int   bestk = 0;

    const int k0 = split * KPER;
    for (int kk = 0; kk < KPER; ++kk) {
        const int k = k0 + kk;
        const float* e = emb + k * DIM;       // uniform across wave -> s_load
        const float e2v = e2[k];
        float acc[4] = {0.f, 0.f, 0.f, 0.f};
#pragma unroll
        for (int i = 0; i < 16; ++i) {
            const float4 v = *reinterpret_cast<const float4*>(e + 4 * i);
            acc[i & 3] = fmaf(v.x, x[4 * i + 0], acc[i & 3]);
            acc[i & 3] = fmaf(v.y, x[4 * i + 1], acc[i & 3]);
            acc[i & 3] = fmaf(v.z, x[4 * i + 2], acc[i & 3]);
            acc[i & 3] = fmaf(v.w, x[4 * i + 3], acc[i & 3]);
        }
        const float dot  = (acc[0] + acc[1]) + (acc[2] + acc[3]);
        const float dist = fmaf(-2.f, dot, e2v);
        if (dist < best) { best = dist; bestk = k; }
    }

    ws[WS_PD + split * N_ROWS + row] = best;
    reinterpret_cast<int*>(ws)[WS_PK + split * N_ROWS + row] = bestk;
}

// ---- merge partials, gather code, STE write, loss, counts ----
__global__ __launch_bounds__(256, 4) void vq_epilogue(
    const float* __restrict__ in, const float* __restrict__ emb,
    float* __restrict__ out, float* __restrict__ ws)
{
    const int row = blockIdx.x * 256 + threadIdx.x;
    const int b   = row >> 10;
    const int hw  = row & 1023;

    float best  = ws[WS_PD + row];
    int   bestk = reinterpret_cast<int*>(ws)[WS_PK + row];
#pragma unroll
    for (int s = 1; s < SPLIT; ++s) {
        const float d = ws[WS_PD + s * N_ROWS + row];
        const int   k = reinterpret_cast<int*>(ws)[WS_PK + s * N_ROWS + row];
        if (d < best || (d == best && k < bestk)) { best = d; bestk = k; }
    }

    atomicAdd(reinterpret_cast<unsigned int*>(ws) + WS_CNT + bestk, 1u);

    const float*  xin  = in  + b * (DIM * HW) + hw;
    float*        outp = out + b * (DIM * HW) + hw;
    const float4* eq   = reinterpret_cast<const float4*>(emb + bestk * DIM);

    float lsum = 0.f;
#pragma unroll
    for (int i = 0; i < 16; ++i) {
        const float4 q = eq[i];
        const float x0 = xin[(4 * i + 0) * HW];
        const float x1 = xin[(4 * i + 1) * HW];
        const float x2 = xin[(4 * i + 2) * HW];
        const float x3 = xin[(4 * i + 3) * HW];
        const float d0 = q.x - x0, d1 = q.y - x1, d2 = q.z - x2, d3 = q.w - x3;
        lsum += d0 * d0 + d1 * d1 + d2 * d2 + d3 * d3;
        outp[(4 * i + 0) * HW] = x0 + d0;   // STE: x + (q - x)
        outp[(4 * i + 1) * HW] = x1 + d1;
        outp[(4 * i + 2) * HW] = x2 + d2;
        outp[(4 * i + 3) * HW] = x3 + d3;
    }

#pragma unroll
    for (int off = 32; off; off >>= 1) lsum += __shfl_down(lsum, off, 64);
    __shared__ float lred[4];
    const int lane = threadIdx.x & 63;
    const int wid  = threadIdx.x >> 6;
    if (lane == 0) lred[wid] = lsum;
    __syncthreads();
    if (threadIdx.x == 0)
        atomicAdd(ws + WS_LOSS, (lred[0] + lred[1]) + (lred[2] + lred[3]));
}

// ---- fallback: fully fused (used only if ws too small for partials) ----
__global__ __launch_bounds__(256, 4) void vq_fused(
    const float* __restrict__ in, const float* __restrict__ emb,
    float* __restrict__ out, float* __restrict__ ws)
{
    const int row = blockIdx.x * 256 + threadIdx.x;
    const int b   = row >> 10;
    const int hw  = row & 1023;

    const float* xin = in + b * (DIM * HW) + hw;
    float x[DIM];
#pragma unroll
    for (int c = 0; c < DIM; ++c) x[c] = xin[c * HW];

    const float* e2 = ws + WS_E2;
    float best  = 3.4e38f;
    int   bestk = 0;
    for (int k = 0; k < K_CODES; ++k) {
        const float* e = emb + k * DIM;
        const float e2v = e2[k];
        float acc[4] = {0.f, 0.f, 0.f, 0.f};
#pragma unroll
        for (int i = 0; i < 16; ++i) {
            const float4 v = *reinterpret_cast<const float4*>(e + 4 * i);
            acc[i & 3] = fmaf(v.x, x[4 * i + 0], acc[i & 3]);
            acc[i & 3] = fmaf(v.y, x[4 * i + 1], acc[i & 3]);
            acc[i & 3] = fmaf(v.z, x[4 * i + 2], acc[i & 3]);
            acc[i & 3] = fmaf(v.w, x[4 * i + 3], acc[i & 3]);
        }
        const float dot  = (acc[0] + acc[1]) + (acc[2] + acc[3]);
        const float dist = fmaf(-2.f, dot, e2v);
        if (dist < best) { best = dist; bestk = k; }
    }

    atomicAdd(reinterpret_cast<unsigned int*>(ws) + WS_CNT + bestk, 1u);

    float*        outp = out + b * (DIM * HW) + hw;
    const float4* eq   = reinterpret_cast<const float4*>(emb + bestk * DIM);
    float lsum = 0.f;
#pragma unroll
    for (int i = 0; i < 16; ++i) {
        const float4 q = eq[i];
        const int c0 = 4 * i;
        const float d0 = q.x - x[c0 + 0], d1 = q.y - x[c0 + 1];
        const float d2 = q.z - x[c0 + 2], d3 = q.w - x[c0 + 3];
        lsum += d0 * d0 + d1 * d1 + d2 * d2 + d3 * d3;
        outp[(c0 + 0) * HW] = x[c0 + 0] + d0;
        outp[(c0 + 1) * HW] = x[c0 + 1] + d1;
        outp[(c0 + 2) * HW] = x[c0 + 2] + d2;
        outp[(c0 + 3) * HW] = x[c0 + 3] + d3;
    }
#pragma unroll
    for (int off = 32; off; off >>= 1) lsum += __shfl_down(lsum, off, 64);
    __shared__ float lred[4];
    const int lane = threadIdx.x & 63;
    const int wid  = threadIdx.x >> 6;
    if (lane == 0) lred[wid] = lsum;
    __syncthreads();
    if (threadIdx.x == 0)
        atomicAdd(ws + WS_LOSS, (lred[0] + lred[1]) + (lred[2] + lred[3]));
}

__global__ void vq_final(float* __restrict__ out, const float* __restrict__ ws) {
    __shared__ float red[16];
    const int t = threadIdx.x;  // 1024 threads
    const unsigned int* counts = reinterpret_cast<const unsigned int*>(ws) + WS_CNT;
    float p = (float)counts[t] * (1.0f / 65536.f);
    float v = p * logf(p + 1e-10f);
#pragma unroll
    for (int off = 32; off; off >>= 1) v += __shfl_down(v, off, 64);
    if ((t & 63) == 0) red[t >> 6] = v;
    __syncthreads();
    if (t == 0) {
        float s = 0.f;
#pragma unroll
        for (int i = 0; i < 16; ++i) s += red[i];
        out[OUT_ELEMS]     = 0.25f * (1.0f / (float)OUT_ELEMS) * ws[WS_LOSS];
        out[OUT_ELEMS + 1] = expf(-s);
    }
}

extern "C" void kernel_launch(void* const* d_in, const int* in_sizes, int n_in,
                              void* d_out, int out_size, void* d_ws, size_t ws_size,
                              hipStream_t stream) {
    const float* in  = (const float*)d_in[0];
    const float* emb = (const float*)d_in[1];
    float* out = (float*)d_out;
    float* ws  = (float*)d_ws;

    vq_init<<<4, 256, 0, stream>>>(emb, ws);
    if (ws_size >= WS_BYTES_NEEDED) {
        vq_argmin<<<(N_ROWS / 256) * SPLIT, 256, 0, stream>>>(in, emb, ws);
        vq_epilogue<<<N_ROWS / 256, 256, 0, stream>>>(in, emb, out, ws);
    } else {
        vq_fused<<<N_ROWS / 256, 256, 0, stream>>>(in, emb, out, ws);
    }
    vq_final<<<1, 1024, 0, stream>>>(out, ws);
}

// Round 3
// 179.583 us; speedup vs baseline: 10.2340x; 1.1125x over previous
//
#include <hip/hip_runtime.h>

// VectorQuantizer (eval fwd): inputs [64,64,32,32] f32 NCHW, embedding [1024,64] f32.
// Outputs concatenated: quantized [64,64,32,32] f32, loss scalar, perplexity scalar.
//
// distances = ||e_k||^2 - 2 x.e_k (row-constant ||x||^2 dropped).
// All lanes scan the SAME code k -> embedding loads wave-uniform -> s_load
// (scalar pipe) -> inner loop is pure v_fma (SGPR e, VGPR x).
// x is PINNED in VGPRs via an opaque asm barrier (round-2 compiler sank the
// x loads into the k-loop: VGPR_Count=40, VALUBusy 40%).
// Parallelism: codes split into SP block-uniform ranges; partial (dist,k)
// lex-merged in the epilogue (preserves first-occurrence argmin).

#define K_CODES 1024
#define DIM 64
#define HW 1024          // 32*32
#define N_ROWS 65536
#define OUT_ELEMS 4194304

// ws layout (float indices)
#define WS_E2   0        // 1024 floats: ||e_k||^2
#define WS_CNT  1024     // 1024 u32: counts
#define WS_LOSS 2048     // 1 float
#define WS_PD   4096     // SP*N_ROWS floats: partial dists; then SP*N_ROWS ints: partial ks

__global__ void vq_init(const float* __restrict__ emb, float* __restrict__ ws) {
    const int k = blockIdx.x * blockDim.x + threadIdx.x;  // 1024 threads total
    if (k < K_CODES) {
        const float4* e4 = reinterpret_cast<const float4*>(emb + k * DIM);
        float s = 0.f;
#pragma unroll
        for (int i = 0; i < DIM / 4; ++i) {
            float4 v = e4[i];
            s += v.x * v.x + v.y * v.y + v.z * v.z + v.w * v.w;
        }
        ws[WS_E2 + k] = s;
        reinterpret_cast<unsigned int*>(ws)[WS_CNT + k] = 0u;
    }
    if (blockIdx.x == 0 && threadIdx.x == 0) ws[WS_LOSS] = 0.f;
}

template <int SP>
__global__ __launch_bounds__(256, 4) void vq_argmin(
    const float* __restrict__ in, const float* __restrict__ emb,
    float* __restrict__ ws)
{
    const int blk   = blockIdx.x;
    const int split = blk % SP;
    const int row   = (blk / SP) * 256 + threadIdx.x;
    const int b     = row >> 10;
    const int hw    = row & 1023;

    const float* xin = in + b * (DIM * HW) + hw;
    float xv[DIM];
#pragma unroll
    for (int c = 0; c < DIM; ++c) xv[c] = xin[c * HW];
    // Pin x in VGPRs: opaque asm may modify xv -> compiler cannot re-load from memory.
#pragma unroll
    for (int c = 0; c < DIM; ++c) asm volatile("" : "+v"(xv[c]));

    const float* e2 = ws + WS_E2;
    float best  = 3.4e38f;
    int   bestk = 0;

    constexpr int KPER = K_CODES / SP;
    const int k0 = split * KPER;
    for (int kk = 0; kk < KPER; ++kk) {
        const int k = k0 + kk;
        const float* e = emb + k * DIM;       // wave-uniform -> s_load
        const float e2v = e2[k];
        float acc[4] = {0.f, 0.f, 0.f, 0.f};
#pragma unroll
        for (int i = 0; i < 16; ++i) {
            const float4 v = *reinterpret_cast<const float4*>(e + 4 * i);
            acc[i & 3] = fmaf(v.x, xv[4 * i + 0], acc[i & 3]);
            acc[i & 3] = fmaf(v.y, xv[4 * i + 1], acc[i & 3]);
            acc[i & 3] = fmaf(v.z, xv[4 * i + 2], acc[i & 3]);
            acc[i & 3] = fmaf(v.w, xv[4 * i + 3], acc[i & 3]);
        }
        const float dot  = (acc[0] + acc[1]) + (acc[2] + acc[3]);
        const float dist = fmaf(-2.f, dot, e2v);
        if (dist < best) { best = dist; bestk = k; }
    }

    ws[WS_PD + split * N_ROWS + row] = best;
    reinterpret_cast<int*>(ws)[WS_PD + SP * N_ROWS + split * N_ROWS + row] = bestk;
}

// 64 rows x 4 channel-groups per 256-thread block.
template <int SP>
__global__ __launch_bounds__(256, 4) void vq_epilogue(
    const float* __restrict__ in, const float* __restrict__ emb,
    float* __restrict__ out, float* __restrict__ ws)
{
    const int tid = threadIdx.x;
    const int row = blockIdx.x * 64 + (tid & 63);
    const int cg  = tid >> 6;          // 0..3 -> channels [16*cg, 16*cg+16)
    const int b   = row >> 10;
    const int hw  = row & 1023;

    const int* pk = reinterpret_cast<const int*>(ws) + WS_PD + SP * N_ROWS;
    float best  = ws[WS_PD + row];
    int   bestk = pk[row];
#pragma unroll
    for (int s = 1; s < SP; ++s) {
        const float d = ws[WS_PD + s * N_ROWS + row];
        const int   k = pk[s * N_ROWS + row];
        if (d < best || (d == best && k < bestk)) { best = d; bestk = k; }
    }

    if (cg == 0)
        atomicAdd(reinterpret_cast<unsigned int*>(ws) + WS_CNT + bestk, 1u);

    const float*  xin  = in  + b * (DIM * HW) + hw;
    float*        outp = out + b * (DIM * HW) + hw;
    const float4* eq   = reinterpret_cast<const float4*>(emb + bestk * DIM + 16 * cg);

    float lsum = 0.f;
#pragma unroll
    for (int i = 0; i < 4; ++i) {
        const float4 q = eq[i];
        const int c0 = 16 * cg + 4 * i;
        const float x0 = xin[(c0 + 0) * HW];
        const float x1 = xin[(c0 + 1) * HW];
        const float x2 = xin[(c0 + 2) * HW];
        const float x3 = xin[(c0 + 3) * HW];
        const float d0 = q.x - x0, d1 = q.y - x1, d2 = q.z - x2, d3 = q.w - x3;
        lsum += d0 * d0 + d1 * d1 + d2 * d2 + d3 * d3;
        outp[(c0 + 0) * HW] = x0 + d0;   // STE: x + (q - x)
        outp[(c0 + 1) * HW] = x1 + d1;
        outp[(c0 + 2) * HW] = x2 + d2;
        outp[(c0 + 3) * HW] = x3 + d3;
    }

#pragma unroll
    for (int off = 32; off; off >>= 1) lsum += __shfl_down(lsum, off, 64);
    __shared__ float lred[4];
    const int lane = tid & 63;
    const int wid  = tid >> 6;
    if (lane == 0) lred[wid] = lsum;
    __syncthreads();
    if (tid == 0)
        atomicAdd(ws + WS_LOSS, (lred[0] + lred[1]) + (lred[2] + lred[3]));
}

// Fallback if ws too small for partials: fully fused.
__global__ __launch_bounds__(256, 4) void vq_fused(
    const float* __restrict__ in, const float* __restrict__ emb,
    float* __restrict__ out, float* __restrict__ ws)
{
    const int row = blockIdx.x * 256 + threadIdx.x;
    const int b   = row >> 10;
    const int hw  = row & 1023;

    const float* xin = in + b * (DIM * HW) + hw;
    float xv[DIM];
#pragma unroll
    for (int c = 0; c < DIM; ++c) xv[c] = xin[c * HW];
#pragma unroll
    for (int c = 0; c < DIM; ++c) asm volatile("" : "+v"(xv[c]));

    const float* e2 = ws + WS_E2;
    float best  = 3.4e38f;
    int   bestk = 0;
    for (int k = 0; k < K_CODES; ++k) {
        const float* e = emb + k * DIM;
        const float e2v = e2[k];
        float acc[4] = {0.f, 0.f, 0.f, 0.f};
#pragma unroll
        for (int i = 0; i < 16; ++i) {
            const float4 v = *reinterpret_cast<const float4*>(e + 4 * i);
            acc[i & 3] = fmaf(v.x, xv[4 * i + 0], acc[i & 3]);
            acc[i & 3] = fmaf(v.y, xv[4 * i + 1], acc[i & 3]);
            acc[i & 3] = fmaf(v.z, xv[4 * i + 2], acc[i & 3]);
            acc[i & 3] = fmaf(v.w, xv[4 * i + 3], acc[i & 3]);
        }
        const float dot  = (acc[0] + acc[1]) + (acc[2] + acc[3]);
        const float dist = fmaf(-2.f, dot, e2v);
        if (dist < best) { best = dist; bestk = k; }
    }

    atomicAdd(reinterpret_cast<unsigned int*>(ws) + WS_CNT + bestk, 1u);

    float*        outp = out + b * (DIM * HW) + hw;
    const float4* eq   = reinterpret_cast<const float4*>(emb + bestk * DIM);
    float lsum = 0.f;
#pragma unroll
    for (int i = 0; i < 16; ++i) {
        const float4 q = eq[i];
        const int c0 = 4 * i;
        const float d0 = q.x - xv[c0 + 0], d1 = q.y - xv[c0 + 1];
        const float d2 = q.z - xv[c0 + 2], d3 = q.w - xv[c0 + 3];
        lsum += d0 * d0 + d1 * d1 + d2 * d2 + d3 * d3;
        outp[(c0 + 0) * HW] = xv[c0 + 0] + d0;
        outp[(c0 + 1) * HW] = xv[c0 + 1] + d1;
        outp[(c0 + 2) * HW] = xv[c0 + 2] + d2;
        outp[(c0 + 3) * HW] = xv[c0 + 3] + d3;
    }
#pragma unroll
    for (int off = 32; off; off >>= 1) lsum += __shfl_down(lsum, off, 64);
    __shared__ float lred[4];
    const int lane = threadIdx.x & 63;
    const int wid  = threadIdx.x >> 6;
    if (lane == 0) lred[wid] = lsum;
    __syncthreads();
    if (threadIdx.x == 0)
        atomicAdd(ws + WS_LOSS, (lred[0] + lred[1]) + (lred[2] + lred[3]));
}

__global__ void vq_final(float* __restrict__ out, const float* __restrict__ ws) {
    __shared__ float red[16];
    const int t = threadIdx.x;  // 1024 threads
    const unsigned int* counts = reinterpret_cast<const unsigned int*>(ws) + WS_CNT;
    float p = (float)counts[t] * (1.0f / 65536.f);
    float v = p * logf(p + 1e-10f);
#pragma unroll
    for (int off = 32; off; off >>= 1) v += __shfl_down(v, off, 64);
    if ((t & 63) == 0) red[t >> 6] = v;
    __syncthreads();
    if (t == 0) {
        float s = 0.f;
#pragma unroll
        for (int i = 0; i < 16; ++i) s += red[i];
        out[OUT_ELEMS]     = 0.25f * (1.0f / (float)OUT_ELEMS) * ws[WS_LOSS];
        out[OUT_ELEMS + 1] = expf(-s);
    }
}

extern "C" void kernel_launch(void* const* d_in, const int* in_sizes, int n_in,
                              void* d_out, int out_size, void* d_ws, size_t ws_size,
                              hipStream_t stream) {
    const float* in  = (const float*)d_in[0];
    const float* emb = (const float*)d_in[1];
    float* out = (float*)d_out;
    float* ws  = (float*)d_ws;

    const size_t need8 = (size_t)(WS_PD + 2 * 8 * N_ROWS) * 4;
    const size_t need4 = (size_t)(WS_PD + 2 * 4 * N_ROWS) * 4;

    vq_init<<<4, 256, 0, stream>>>(emb, ws);
    if (ws_size >= need8) {
        vq_argmin<8><<<(N_ROWS / 256) * 8, 256, 0, stream>>>(in, emb, ws);
        vq_epilogue<8><<<N_ROWS / 64, 256, 0, stream>>>(in, emb, out, ws);
    } else if (ws_size >= need4) {
        vq_argmin<4><<<(N_ROWS / 256) * 4, 256, 0, stream>>>(in, emb, ws);
        vq_epilogue<4><<<N_ROWS / 64, 256, 0, stream>>>(in, emb, out, ws);
    } else {
        vq_fused<<<N_ROWS / 256, 256, 0, stream>>>(in, emb, out, ws);
    }
    vq_final<<<1, 1024, 0, stream>>>(out, ws);
}